// Round 5
// baseline (1441.625 us; speedup 1.0000x reference)
//
#include <hip/hip_runtime.h>
#include <math.h>

#define TOKENS 16384
#define EMBD   4096
#define NEXP   64
#define TOPK   8
#define KSPLIT 8
#define KSLICE (EMBD / KSPLIT)   /* 512 */
#define CHUNK  16
#define EHALF  32                /* experts per wave (64 split across wave pairs) */

// ---------------------------------------------------------------------------
// Kernel 1: transpose W[64][4096] -> Wt[4096][64], LDS-tiled, coalesced both
// directions (kept from round 4 -- benign; round-4 regression was all gemm).
// ---------------------------------------------------------------------------
__global__ __launch_bounds__(256) void transpose_w(const float* __restrict__ W,
                                                   float* __restrict__ Wt) {
    __shared__ float tile[64][65];
    const int t = threadIdx.x;
    const int kbase = blockIdx.x * 64;

#pragma unroll
    for (int i = 0; i < 16; ++i) {
        const int e = i * 4 + (t >> 6);
        const int k = t & 63;
        tile[e][k] = W[e * EMBD + kbase + k];
    }
    __syncthreads();
#pragma unroll
    for (int i = 0; i < 16; ++i) {
        const int kr = i * 4 + (t >> 6);
        const int e  = t & 63;
        Wt[(size_t)(kbase + kr) * NEXP + e] = tile[e][kr];
    }
}

// ---------------------------------------------------------------------------
// Kernel 2: partial GEMM. EXACT round-2 geometry (1024 x 256-thread blocks,
// wave pairs share 64-token groups -> x reuse hits L1; round 4 proved
// smaller blocks kill this: FETCH 225->736 MB). One change vs round 2:
// x loads software-pipelined by loop PEELING -- prefetch address is affine
// (xrow + kc + CHUNK, no ternary; the round-3 ternary de-pipelined the loop,
// VGPR collapsed to 44). Next chunk's 4 float4 loads issue before this
// chunk's 512 FMAs -> ~1000 VALU cycles cover the L2 latency.
// Numerics: per-(token,expert) FMA chain / chunk boundaries / f64 outer
// accumulation untouched -> logits BIT-IDENTICAL to every passing version.
// Grid: (TOKENS/128) x KSPLIT = 1024 blocks of 256.
// ---------------------------------------------------------------------------
__global__ __launch_bounds__(256, 3) void gemm_partial(
    const float* __restrict__ x, const float* __restrict__ Wt,
    float* __restrict__ part) {
    const int lane = threadIdx.x & 63;
    const int wave = threadIdx.x >> 6;
    const int tgrp = wave >> 1;                     // token group within block
    const int half = __builtin_amdgcn_readfirstlane(wave & 1);  // SGPR-hoisted
    const int tok  = blockIdx.x * 128 + tgrp * 64 + lane;
    const int ks   = blockIdx.y;
    const int kbase = ks * KSLICE;

    const float* xrow  = x + (size_t)tok * EMBD + kbase;
    const float* wbase = Wt + (size_t)kbase * NEXP + half * EHALF;  // wave-uniform

    double accd[EHALF];
#pragma unroll
    for (int e = 0; e < EHALF; ++e) accd[e] = 0.0;

    // one chunk of FMAs (inlined); identical body/order to round 2
    auto do_chunk = [&](int kc, float4 a, float4 b, float4 c, float4 d4) {
        float xv[CHUNK] = {a.x, a.y, a.z, a.w,  b.x, b.y, b.z, b.w,
                           c.x, c.y, c.z, c.w,  d4.x, d4.y, d4.z, d4.w};
        float accf[EHALF];
#pragma unroll
        for (int e = 0; e < EHALF; ++e) accf[e] = 0.0f;
#pragma unroll
        for (int j = 0; j < CHUNK; ++j) {
            const float xj = xv[j];
            const float* wrow = wbase + (size_t)(kc + j) * NEXP;  // wave-uniform
#pragma unroll
            for (int e = 0; e < EHALF; ++e)
                accf[e] = fmaf(wrow[e], xj, accf[e]);
        }
#pragma unroll
        for (int e = 0; e < EHALF; ++e) accd[e] += (double)accf[e];
    };

    // prologue: load chunk 0
    float4 n0, n1, n2, n3;
    {
        const float4* xp = (const float4*)xrow;
        n0 = xp[0]; n1 = xp[1]; n2 = xp[2]; n3 = xp[3];
    }

    // steady state: prefetch chunk kc+16 (affine address), compute chunk kc
    for (int kc = 0; kc < KSLICE - CHUNK; kc += CHUNK) {
        float4 a = n0, b = n1, c = n2, d4 = n3;
        const float4* xp = (const float4*)(xrow + kc + CHUNK);
        n0 = xp[0]; n1 = xp[1]; n2 = xp[2]; n3 = xp[3];
        do_chunk(kc, a, b, c, d4);
    }
    // epilogue: last chunk
    do_chunk(KSLICE - CHUNK, n0, n1, n2, n3);

    float4* dst = (float4*)(part + ((size_t)ks * TOKENS + tok) * NEXP
                            + (size_t)half * EHALF);
#pragma unroll
    for (int v = 0; v < EHALF / 4; ++v)
        dst[v] = make_float4((float)accd[4 * v],     (float)accd[4 * v + 1],
                             (float)accd[4 * v + 2], (float)accd[4 * v + 3]);
}

// ---------------------------------------------------------------------------
// Kernel 3: reduce K-split partials (fixed order f64 -> logits bit-identical),
// RANK-BASED top-8 (ties -> lower index, matching jax.lax.top_k), masked
// softmax. One wave per token, 4 tokens per block. Unchanged since round 2.
// ---------------------------------------------------------------------------
__global__ __launch_bounds__(256) void topk_softmax(
    const float* __restrict__ part, float* __restrict__ probs,
    float* __restrict__ idxout) {
    __shared__ float lval[4][NEXP];
    __shared__ float lidx[4][TOPK];

    const int lane = threadIdx.x & 63;   // = expert
    const int wave = threadIdx.x >> 6;
    const int tok  = blockIdx.x * 4 + wave;

    double d = 0.0;
#pragma unroll
    for (int s = 0; s < KSPLIT; ++s)
        d += (double)part[((size_t)s * TOKENS + tok) * NEXP + lane];
    const float logit = (float)d;

    lval[wave][lane] = logit;
    __syncthreads();

    const float4* lv4 = (const float4*)lval[wave];  // broadcast reads
    int rank = 0;
    float m = -INFINITY;
#pragma unroll
    for (int q4 = 0; q4 < NEXP / 4; ++q4) {
        float4 v = lv4[q4];
        const int qb = q4 * 4;
        rank += (v.x > logit || (v.x == logit && qb + 0 < lane)) ? 1 : 0;
        rank += (v.y > logit || (v.y == logit && qb + 1 < lane)) ? 1 : 0;
        rank += (v.z > logit || (v.z == logit && qb + 2 < lane)) ? 1 : 0;
        rank += (v.w > logit || (v.w == logit && qb + 3 < lane)) ? 1 : 0;
        m = fmaxf(fmaxf(m, v.x), fmaxf(v.y, fmaxf(v.z, v.w)));
    }

    const bool sel = rank < TOPK;
    const float t  = sel ? expf(logit - m) : 0.0f;

    float denom = t;
#pragma unroll
    for (int off = 32; off > 0; off >>= 1)
        denom += __shfl_xor(denom, off);

    if (sel) lidx[wave][rank] = (float)lane;   // scatter index by rank
    __syncthreads();

    probs[(size_t)tok * NEXP + lane] = sel ? (t / denom) : 0.0f;
    if (lane < TOPK) idxout[(size_t)tok * TOPK + lane] = lidx[wave][lane];
}

// ---------------------------------------------------------------------------
extern "C" void kernel_launch(void* const* d_in, const int* in_sizes, int n_in,
                              void* d_out, int out_size, void* d_ws, size_t ws_size,
                              hipStream_t stream) {
    const float* x = (const float*)d_in[0];   // [4,4096,4096]
    const float* W = (const float*)d_in[1];   // [64,4096]

    float* out    = (float*)d_out;
    float* probs  = out;                         // 16384*64 floats
    float* idxout = out + (size_t)TOKENS * NEXP; // 16384*8 floats (indices as float)

    float* Wt   = (float*)d_ws;                  // 4096*64 floats = 1 MB
    float* part = Wt + (size_t)EMBD * NEXP;      // 8*16384*64 floats = 32 MB

    hipLaunchKernelGGL(transpose_w, dim3(EMBD / 64), dim3(256), 0, stream,
                       W, Wt);
    hipLaunchKernelGGL(gemm_partial, dim3(TOKENS / 128, KSPLIT), dim3(256), 0, stream,
                       x, Wt, part);
    hipLaunchKernelGGL(topk_softmax, dim3(TOKENS / 4), dim3(256), 0, stream,
                       part, probs, idxout);
}

// Round 6
// 434.356 us; speedup vs baseline: 3.3190x; 3.3190x over previous
//
#include <hip/hip_runtime.h>
#include <math.h>

#define TOKENS 16384
#define EMBD   4096
#define NEXP   64
#define TOPK   8
#define KSPLIT 8
#define KSLICE (EMBD / KSPLIT)   /* 512 */
#define CHUNK  16
#define EHALF  32                /* experts per wave (64 split across wave pairs) */

// ---------------------------------------------------------------------------
// Kernel 1: transpose W[64][4096] -> Wt[4096][64], LDS-tiled, coalesced both
// directions (benign; round-4 regression was entirely gemm FETCH inflation).
// ---------------------------------------------------------------------------
__global__ __launch_bounds__(256) void transpose_w(const float* __restrict__ W,
                                                   float* __restrict__ Wt) {
    __shared__ float tile[64][65];
    const int t = threadIdx.x;
    const int kbase = blockIdx.x * 64;

#pragma unroll
    for (int i = 0; i < 16; ++i) {
        const int e = i * 4 + (t >> 6);
        const int k = t & 63;
        tile[e][k] = W[e * EMBD + kbase + k];
    }
    __syncthreads();
#pragma unroll
    for (int i = 0; i < 16; ++i) {
        const int kr = i * 4 + (t >> 6);
        const int e  = t & 63;
        Wt[(size_t)(kbase + kr) * NEXP + e] = tile[e][kr];
    }
}

// ---------------------------------------------------------------------------
// Kernel 2: partial GEMM — VERBATIM round-2 source (best measured: 166us,
// VGPR=64, SGPR=112, FETCH=225MB, WRITE=34MB). DO NOT RESTRUCTURE THIS LOOP:
//  - r3: ternary prefetch addr  -> de-pipelined, 210us
//  - r4: 128-thread blocks      -> x-reuse died, FETCH 3x, 255us
//  - r5: lambda + loop peel     -> SGPR 112->48 (W loads de-scalarized),
//        WRITE 34MB->2.16GB (scratch), 1190us
// The compiler compiles exactly THIS shape well: straight kc loop, inline
// body, wave-uniform wrow pointer, 256-thread blocks with wave-pair token
// sharing. Remaining stall (~94us over the 72us issue floor) is the
// SGPR-budget-limited s_load pipeline on W -- not addressable at source
// level without breaking one of the above.
// Grid: (TOKENS/128) x KSPLIT = 1024 blocks of 256.
// ---------------------------------------------------------------------------
__global__ __launch_bounds__(256, 3) void gemm_partial(
    const float* __restrict__ x, const float* __restrict__ Wt,
    float* __restrict__ part) {
    const int lane = threadIdx.x & 63;
    const int wave = threadIdx.x >> 6;
    const int tgrp = wave >> 1;                     // token group within block
    // expert half: wave-uniform in fact, but threadIdx-derived -> hoist to
    // SGPR so the W loads stay scalar (s_load) instead of per-lane vector.
    const int half = __builtin_amdgcn_readfirstlane(wave & 1);
    const int tok  = blockIdx.x * 128 + tgrp * 64 + lane;
    const int ks   = blockIdx.y;
    const int kbase = ks * KSLICE;

    const float* xrow  = x + (size_t)tok * EMBD + kbase;
    const float* wbase = Wt + (size_t)kbase * NEXP + half * EHALF;  // wave-uniform

    double accd[EHALF];
#pragma unroll
    for (int e = 0; e < EHALF; ++e) accd[e] = 0.0;

    for (int kc = 0; kc < KSLICE; kc += CHUNK) {
        const float4* xp = (const float4*)(xrow + kc);
        float4 a = xp[0], b = xp[1], c = xp[2], d4 = xp[3];
        float xv[CHUNK] = {a.x, a.y, a.z, a.w,  b.x, b.y, b.z, b.w,
                           c.x, c.y, c.z, c.w,  d4.x, d4.y, d4.z, d4.w};

        float accf[EHALF];
#pragma unroll
        for (int e = 0; e < EHALF; ++e) accf[e] = 0.0f;

#pragma unroll
        for (int j = 0; j < CHUNK; ++j) {
            const float xj = xv[j];
            const float* wrow = wbase + (size_t)(kc + j) * NEXP;  // wave-uniform
#pragma unroll
            for (int e = 0; e < EHALF; ++e)
                accf[e] = fmaf(wrow[e], xj, accf[e]);
        }

#pragma unroll
        for (int e = 0; e < EHALF; ++e) accd[e] += (double)accf[e];
    }

    float4* dst = (float4*)(part + ((size_t)ks * TOKENS + tok) * NEXP
                            + (size_t)half * EHALF);
#pragma unroll
    for (int v = 0; v < EHALF / 4; ++v)
        dst[v] = make_float4((float)accd[4 * v],     (float)accd[4 * v + 1],
                             (float)accd[4 * v + 2], (float)accd[4 * v + 3]);
}

// ---------------------------------------------------------------------------
// Kernel 3: reduce K-split partials (fixed order f64 -> logits bit-identical),
// RANK-BASED top-8 (ties -> lower index, matching jax.lax.top_k), masked
// softmax. One wave per token, 4 tokens per block. Unchanged since round 2.
// ---------------------------------------------------------------------------
__global__ __launch_bounds__(256) void topk_softmax(
    const float* __restrict__ part, float* __restrict__ probs,
    float* __restrict__ idxout) {
    __shared__ float lval[4][NEXP];
    __shared__ float lidx[4][TOPK];

    const int lane = threadIdx.x & 63;   // = expert
    const int wave = threadIdx.x >> 6;
    const int tok  = blockIdx.x * 4 + wave;

    double d = 0.0;
#pragma unroll
    for (int s = 0; s < KSPLIT; ++s)
        d += (double)part[((size_t)s * TOKENS + tok) * NEXP + lane];
    const float logit = (float)d;

    lval[wave][lane] = logit;
    __syncthreads();

    const float4* lv4 = (const float4*)lval[wave];  // broadcast reads
    int rank = 0;
    float m = -INFINITY;
#pragma unroll
    for (int q4 = 0; q4 < NEXP / 4; ++q4) {
        float4 v = lv4[q4];
        const int qb = q4 * 4;
        rank += (v.x > logit || (v.x == logit && qb + 0 < lane)) ? 1 : 0;
        rank += (v.y > logit || (v.y == logit && qb + 1 < lane)) ? 1 : 0;
        rank += (v.z > logit || (v.z == logit && qb + 2 < lane)) ? 1 : 0;
        rank += (v.w > logit || (v.w == logit && qb + 3 < lane)) ? 1 : 0;
        m = fmaxf(fmaxf(m, v.x), fmaxf(v.y, fmaxf(v.z, v.w)));
    }

    const bool sel = rank < TOPK;
    const float t  = sel ? expf(logit - m) : 0.0f;

    float denom = t;
#pragma unroll
    for (int off = 32; off > 0; off >>= 1)
        denom += __shfl_xor(denom, off);

    if (sel) lidx[wave][rank] = (float)lane;   // scatter index by rank
    __syncthreads();

    probs[(size_t)tok * NEXP + lane] = sel ? (t / denom) : 0.0f;
    if (lane < TOPK) idxout[(size_t)tok * TOPK + lane] = lidx[wave][lane];
}

// ---------------------------------------------------------------------------
extern "C" void kernel_launch(void* const* d_in, const int* in_sizes, int n_in,
                              void* d_out, int out_size, void* d_ws, size_t ws_size,
                              hipStream_t stream) {
    const float* x = (const float*)d_in[0];   // [4,4096,4096]
    const float* W = (const float*)d_in[1];   // [64,4096]

    float* out    = (float*)d_out;
    float* probs  = out;                         // 16384*64 floats
    float* idxout = out + (size_t)TOKENS * NEXP; // 16384*8 floats (indices as float)

    float* Wt   = (float*)d_ws;                  // 4096*64 floats = 1 MB
    float* part = Wt + (size_t)EMBD * NEXP;      // 8*16384*64 floats = 32 MB

    hipLaunchKernelGGL(transpose_w, dim3(EMBD / 64), dim3(256), 0, stream,
                       W, Wt);
    hipLaunchKernelGGL(gemm_partial, dim3(TOKENS / 128, KSPLIT), dim3(256), 0, stream,
                       x, Wt, part);
    hipLaunchKernelGGL(topk_softmax, dim3(TOKENS / 4), dim3(256), 0, stream,
                       part, probs, idxout);
}